// Round 11
// baseline (175.889 us; speedup 1.0000x reference)
//
#include <hip/hip_runtime.h>
#include <hip/hip_bf16.h>

#define S_LEN 2048
#define EMB   1024
#define NH    16
#define HD    64
#define BATCH 2
#define MROWS (BATCH * S_LEN)   // 4096

typedef __attribute__((ext_vector_type(8))) short short8;   // 8 bf16 = 4 VGPR
typedef __attribute__((ext_vector_type(4))) float float4v;  // 4 fp32

#define MFMA16(a, b, c) __builtin_amdgcn_mfma_f32_16x16x32_bf16((a), (b), (c), 0, 0, 0)

typedef unsigned short u16;
typedef unsigned int   u32;

__device__ __forceinline__ u16 f2bf(float f) {
    union { float f; u32 u; } v; v.f = f;
    u32 u = v.u;
    return (u16)((u + 0x7fffu + ((u >> 16) & 1u)) >> 16);  // RNE
}

// packed fp32x2 -> bf16x2 (HW RNE on gfx950; fallback manual)
#if __has_builtin(__builtin_amdgcn_cvt_pk_bf16_f32)
typedef __attribute__((ext_vector_type(2))) __bf16 bfx2;
__device__ __forceinline__ u32 pkbf(float a, float b) {
    union { bfx2 v; u32 u; } c;
    c.v = __builtin_amdgcn_cvt_pk_bf16_f32(a, b);
    return c.u;
}
#else
__device__ __forceinline__ u32 pkbf(float a, float b) {
    return (u32)f2bf(a) | ((u32)f2bf(b) << 16);
}
#endif

#if __has_builtin(__builtin_amdgcn_exp2f)
#define EXP2(x) __builtin_amdgcn_exp2f(x)
#else
#define EXP2(x) exp2f(x)
#endif

// async 16B global->LDS (lds dest = wave-uniform base + lane*16)
typedef __attribute__((address_space(3))) unsigned char lds_u8;
typedef __attribute__((address_space(1))) const unsigned char glb_u8;
__device__ __forceinline__ void async_copy16(const void* g, void* l) {
    __builtin_amdgcn_global_load_lds((glb_u8*)g, (lds_u8*)l, 16, 0, 0);
}

// ---------------------------------------------------------------------------
// K0: fused prologue (R9-verified). z=0..3: convert+transpose weight z on
// 64x64 tiles — float4 (16 B/lane) reads, LDS [64][65] staging, uint2
// (4 bf16, 8 B/lane) packed stores via cvt_pk. Wq pre-scaled by 0.125*log2e.
// z=4..7: x -> bf16, 16 floats per thread.
// Coverage: 4 z x 256 blk x 256 thr x 16 = 4,194,304 floats = |x|.
// ---------------------------------------------------------------------------
__global__ __launch_bounds__(256) void prep_kernel(
    const float* __restrict__ x,
    const float* __restrict__ W0, const float* __restrict__ W1,
    const float* __restrict__ W2, const float* __restrict__ W3,
    u16* __restrict__ xb, u16* __restrict__ Wt) {
    const int z = blockIdx.z;
    const int tid = threadIdx.x;
    if (z >= 4) {
        int i = ((((z - 4) * 256) + blockIdx.y * 16 + blockIdx.x) * 256 + tid) * 16;
#pragma unroll
        for (int k = 0; k < 4; ++k) {
            float4 f = *(const float4*)(x + i + k * 4);
            uint2 o; o.x = pkbf(f.x, f.y); o.y = pkbf(f.z, f.w);
            *(uint2*)(xb + i + k * 4) = o;
        }
        return;
    }
    const float* W = (z == 0) ? W0 : (z == 1) ? W1 : (z == 2) ? W2 : W3;
    u16* dst = Wt + (size_t)z * EMB * EMB;
    const float sc = (z == 0) ? 0.18033688011112042f : 1.0f;
    __shared__ float tile[64][65];
    const int c0 = blockIdx.x * 64, r0 = blockIdx.y * 64;
    const int rv = tid & 15, rw = tid >> 4;
#pragma unroll
    for (int k = 0; k < 4; ++k) {
        int row = rw + 16 * k;
        float4 f = *(const float4*)&W[(size_t)(r0 + row) * EMB + c0 + rv * 4];
        tile[row][rv * 4 + 0] = f.x;
        tile[row][rv * 4 + 1] = f.y;
        tile[row][rv * 4 + 2] = f.z;
        tile[row][rv * 4 + 3] = f.w;
    }
    __syncthreads();
    const int rq = tid & 15, cw = tid >> 4;
#pragma unroll
    for (int k = 0; k < 4; ++k) {
        int cr = cw + 16 * k;
        float t0 = tile[rq * 4 + 0][cr] * sc;
        float t1 = tile[rq * 4 + 1][cr] * sc;
        float t2 = tile[rq * 4 + 2][cr] * sc;
        float t3 = tile[rq * 4 + 3][cr] * sc;
        uint2 o; o.x = pkbf(t0, t1); o.y = pkbf(t2, t3);
        *(uint2*)&dst[(size_t)(c0 + cr) * EMB + r0 + rq * 4] = o;
    }
}

// ---------------------------------------------------------------------------
// K2: fused 3-projection GEMM (R11: T4 counted-vmcnt, mirrors R10's attn
// win). 3-deep LDS K-pipeline: stage K-step kt+2 during kt; barrier is
// s_waitcnt vmcnt(4) lgkmcnt(0) + s_barrier (kt+1's 4 loads/wave drained,
// kt+2's 4 stay IN FLIGHT across the barrier — never vmcnt(0) mid-loop).
// Slot safety mod 3: read kt, landing kt+1, issuing kt+2 == kt-1 (last read
// one lgkm-drained barrier ago). LDS = 48 KiB -> 3 blocks/CU (144 KiB) at
// grid 768. Epilogue unchanged. z=0 Q, z=1 K, z=2 V^T.
// ---------------------------------------------------------------------------
__global__ __launch_bounds__(256) void gemm_proj_kernel(
    const u16* __restrict__ A, const u16* __restrict__ WtAll,
    u16* __restrict__ Qb, u16* __restrict__ Kb, u16* __restrict__ Vtb) {
    const int z = blockIdx.z;
    const u16* Wt = WtAll + (size_t)z * EMB * EMB;
    const int tid = threadIdx.x;
    const int lane = tid & 63, wid = tid >> 6;
    const int wm = wid >> 1, wn = wid & 1;
    const int l15 = lane & 15, lq = lane >> 4;
    const int m0 = blockIdx.y * 128, n0 = blockIdx.x * 128;
    const u16* Ag = A;
    const u16* Bg = Wt;
    __shared__ u16 As[3][128][32];
    __shared__ u16 Bs[3][128][32];
    float4v acc[4][4] = {};
    const int rr = lane >> 2;
    const int cc = ((lane & 3) ^ ((rr >> 1) & 3)) * 8;
    const int ca = (lq ^ ((l15 >> 1) & 3)) * 8;

#define PJ_STAGE(SLOT, KN)                                                                     \
    for (int wl = wid; wl < 8; wl += 4) {                                                      \
        async_copy16(&Ag[(size_t)(m0 + wl * 16 + rr) * EMB + (KN) + cc], &As[SLOT][wl * 16][0]); \
        async_copy16(&Bg[(size_t)(n0 + wl * 16 + rr) * EMB + (KN) + cc], &Bs[SLOT][wl * 16][0]); \
    }

    PJ_STAGE(0, 0)
    PJ_STAGE(1, 32)
    asm volatile("s_waitcnt vmcnt(4)" ::: "memory");
    __builtin_amdgcn_s_barrier();

    int slr = 0, slw = 2;
    for (int kt = 0; kt < 32; ++kt) {
        if (kt < 30) PJ_STAGE(slw, (kt + 2) * 32)
        short8 a[4], b[4];
#pragma unroll
        for (int i = 0; i < 4; ++i) a[i] = *(const short8*)&As[slr][wm * 64 + i * 16 + l15][ca];
#pragma unroll
        for (int j = 0; j < 4; ++j) b[j] = *(const short8*)&Bs[slr][wn * 64 + j * 16 + l15][ca];
#pragma unroll
        for (int i = 0; i < 4; ++i)
#pragma unroll
            for (int j = 0; j < 4; ++j)
                acc[i][j] = MFMA16(a[i], b[j], acc[i][j]);
        if (kt < 30) {
            asm volatile("s_waitcnt vmcnt(4) lgkmcnt(0)" ::: "memory");
        } else {
            asm volatile("s_waitcnt vmcnt(0) lgkmcnt(0)" ::: "memory");
        }
        __builtin_amdgcn_s_barrier();
        slr = (slr == 2) ? 0 : slr + 1;
        slw = (slw == 2) ? 0 : slw + 1;
    }

#pragma unroll
    for (int i = 0; i < 4; ++i)
#pragma unroll
        for (int j = 0; j < 4; ++j) {
            int mb = m0 + wm * 64 + i * 16 + lq * 4;      // 4 consecutive m
            int n  = n0 + wn * 64 + j * 16 + l15;
            int b_ = mb >> 11, s = mb & 2047;
            int h = n >> 6, d = n & 63;
            if (z == 2) {
                uint2 pv;
                pv.x = pkbf(acc[i][j][0], acc[i][j][1]);
                pv.y = pkbf(acc[i][j][2], acc[i][j][3]);
                *(uint2*)&Vtb[(((size_t)(b_ * NH + h) * HD + d) * S_LEN) + s] = pv;
            } else {
                u16* dst = (z == 1) ? Kb : Qb;
#pragma unroll
                for (int r = 0; r < 4; ++r)
                    dst[(((size_t)(b_ * NH + h) * S_LEN + s + r) * HD) + d] = f2bf(acc[i][j][r]);
            }
        }
}

// ---------------------------------------------------------------------------
// K4: output GEMM -> fp32 (R11: same T4 counted-vmcnt 3-deep pipeline;
// 3 loads/wave per stage -> vmcnt(3)). 128m x 64n tiles, grid (16,32).
// LDS = As[3] 24K + Bs[3] 12K = 36 KiB.
// ---------------------------------------------------------------------------
__global__ __launch_bounds__(256) void gemm_out_kernel(
    const u16* __restrict__ A, const u16* __restrict__ Wt, float* __restrict__ out) {
    const int tid = threadIdx.x;
    const int lane = tid & 63, wid = tid >> 6;
    const int wm = wid >> 1, wn = wid & 1;
    const int l15 = lane & 15, lq = lane >> 4;
    const int m0 = blockIdx.y * 128, n0 = blockIdx.x * 64;
    __shared__ u16 As[3][128][32];
    __shared__ u16 Bs[3][64][32];
    float4v acc[4][2] = {};
    const int rr = lane >> 2;
    const int cc = ((lane & 3) ^ ((rr >> 1) & 3)) * 8;
    const int ca = (lq ^ ((l15 >> 1) & 3)) * 8;

#define GOUT_STAGE(SLOT, KN)                                                                   \
    {                                                                                           \
        for (int wl = wid; wl < 8; wl += 4)                                                     \
            async_copy16(&A[(size_t)(m0 + wl * 16 + rr) * EMB + (KN) + cc], &As[SLOT][wl * 16][0]); \
        async_copy16(&Wt[(size_t)(n0 + wid * 16 + rr) * EMB + (KN) + cc], &Bs[SLOT][wid * 16][0]); \
    }

    GOUT_STAGE(0, 0)
    GOUT_STAGE(1, 32)
    asm volatile("s_waitcnt vmcnt(3)" ::: "memory");
    __builtin_amdgcn_s_barrier();

    int slr = 0, slw = 2;
    for (int kt = 0; kt < 32; ++kt) {
        if (kt < 30) GOUT_STAGE(slw, (kt + 2) * 32)
        short8 a[4], b[2];
#pragma unroll
        for (int i = 0; i < 4; ++i) a[i] = *(const short8*)&As[slr][wm * 64 + i * 16 + l15][ca];
#pragma unroll
        for (int j = 0; j < 2; ++j) b[j] = *(const short8*)&Bs[slr][wn * 32 + j * 16 + l15][ca];
#pragma unroll
        for (int i = 0; i < 4; ++i)
#pragma unroll
            for (int j = 0; j < 2; ++j)
                acc[i][j] = MFMA16(a[i], b[j], acc[i][j]);
        if (kt < 30) {
            asm volatile("s_waitcnt vmcnt(3) lgkmcnt(0)" ::: "memory");
        } else {
            asm volatile("s_waitcnt vmcnt(0) lgkmcnt(0)" ::: "memory");
        }
        __builtin_amdgcn_s_barrier();
        slr = (slr == 2) ? 0 : slr + 1;
        slw = (slw == 2) ? 0 : slw + 1;
    }

#pragma unroll
    for (int i = 0; i < 4; ++i)
#pragma unroll
        for (int j = 0; j < 2; ++j)
#pragma unroll
            for (int r = 0; r < 4; ++r) {
                int m = m0 + wm * 64 + i * 16 + lq * 4 + r;
                int n = n0 + wn * 32 + j * 16 + l15;
                out[(size_t)m * EMB + n] = acc[i][j][r];
            }
}

// ---------------------------------------------------------------------------
// K3: flash attention (causal), S^T = K*Q^T, fixed-shift softmax (m=0).
// R10-verified (171.7us total): R1 data path + T4 counted-vmcnt pipeline.
// K/V 4-deep; stage tile t+2 during tile t; barrier = s_waitcnt vmcnt(4)
// lgkmcnt(0) + s_barrier (tile t+1's 4 loads drained, t+2's in flight).
// LDS = Ks[4]+Vs[4]+Ps = 80 KiB -> 2 blocks/CU exactly (grid 512 = 2/CU).
// ---------------------------------------------------------------------------
#define ATTN_STAGE(SLOT, T)                                                                    \
    {                                                                                           \
        int kv0s = (T) * 64;                                                                    \
        u16 (*KsD)[64] = Ks[SLOT];                                                              \
        u16 (*VsD)[64] = Vs[SLOT];                                                              \
        for (int wl = wid; wl < 8; wl += 4) {                                                   \
            async_copy16(&Kb[(size_t)(kv0s + wl * 8 + rr8) * HD + cc8], &KsD[wl * 8][0]);       \
            async_copy16(&Vb[(size_t)(wl * 8 + rr8) * S_LEN + kv0s + cc8], &VsD[wl * 8][0]);    \
        }                                                                                       \
    }

// QK + mask + exp2 + pack + swizzled Ps write (no drain, no PV)
#define ATTN_QKSM(KF, T, QF, PS, QW)                                                           \
    {                                                                                           \
        const int kv0 = (T) * 64;                                                               \
        float4v sc[4];                                                                          \
        _Pragma("unroll")                                                                       \
        for (int nt = 0; nt < 4; ++nt) {                                                        \
            float4v c4 = {};                                                                    \
            c4 = MFMA16(KF[nt][0], QF[0], c4);                                                  \
            c4 = MFMA16(KF[nt][1], QF[1], c4);                                                  \
            sc[nt] = c4;                                                                        \
        }                                                                                       \
        if (kv0 + 63 > (QW)) {                                                                  \
            const int qi = (QW) + l15;                                                          \
            _Pragma("unroll")                                                                   \
            for (int nt = 0; nt < 4; ++nt)                                                      \
                _Pragma("unroll")                                                               \
                for (int r = 0; r < 4; ++r)                                                     \
                    if (kv0 + nt * 16 + lq * 4 + r > qi) sc[nt][r] = -__builtin_inff();         \
        }                                                                                       \
        _Pragma("unroll")                                                                       \
        for (int nt = 0; nt < 4; ++nt) {                                                        \
            float p0 = EXP2(sc[nt][0]);                                                         \
            float p1 = EXP2(sc[nt][1]);                                                         \
            float p2 = EXP2(sc[nt][2]);                                                         \
            float p3 = EXP2(sc[nt][3]);                                                         \
            uint2 pk;                                                                           \
            pk.x = pkbf(p0, p1);                                                                \
            pk.y = pkbf(p2, p3);                                                                \
            *(uint2*)((char*)&PS[l15][0] +                                                      \
                      (((nt * 2 + (lq >> 1)) ^ swp) * 16 + (lq & 1) * 8)) = pk;                 \
        }                                                                                       \
    }

#define ATTN_PV(PS, VF, OO, LS)                                                                \
    {                                                                                           \
        _Pragma("unroll")                                                                       \
        for (int kk = 0; kk < 2; ++kk) {                                                        \
            short8 pf = *(const short8*)((const char*)&PS[l15][0] +                             \
                                         (((kk * 4 + lq) ^ swp) * 16));                         \
            _Pragma("unroll")                                                                   \
            for (int nd = 0; nd < 4; ++nd)                                                      \
                OO[nd] = MFMA16(pf, VF[kk][nd], OO[nd]);                                        \
            LS = MFMA16(pf, ones8, LS);                                                         \
        }                                                                                       \
    }

#define ATTN_EPI(OO, LS, Q0)                                                                   \
    {                                                                                           \
        _Pragma("unroll")                                                                       \
        for (int r = 0; r < 4; ++r) {                                                           \
            float lr = 1.f / LS[r];                                                             \
            int s = (Q0) + wid * 16 + lq * 4 + r;                                               \
            size_t base = ((size_t)b * S_LEN + s) * EMB + h * HD;                               \
            _Pragma("unroll")                                                                   \
            for (int nd = 0; nd < 4; ++nd)                                                      \
                ctx[base + nd * 16 + l15] = f2bf(OO[nd][r] * lr);                               \
        }                                                                                       \
    }

__global__ __launch_bounds__(256, 2) void attn_kernel(
    const u16* __restrict__ Q, const u16* __restrict__ K,
    const u16* __restrict__ Vt, u16* __restrict__ ctx) {
    const int tid = threadIdx.x;
    const int lane = tid & 63, wid = tid >> 6;
    const int l15 = lane & 15, lq = lane >> 4;
    const int bh = blockIdx.x;               // x fastest: same-bh blocks same XCD
    const int b = bh >> 4, h = bh & 15;
    const int y = blockIdx.y;                // 0..15
    const int qa = y, qh = 31 - y;           // paired q-tiles: 33 units/block
    const int q0h = qh * 64, q0a = qa * 64;
    const int qwh = q0h + wid * 16, qwa = q0a + wid * 16;

    const u16* Qb = Q + (size_t)bh * S_LEN * HD;
    const u16* Kb = K + (size_t)bh * S_LEN * HD;
    const u16* Vb = Vt + (size_t)bh * HD * S_LEN;

    __shared__ u16 Ks[4][64][64];      // [kv][d], 4-deep, xor-swizzled (32 KB)
    __shared__ u16 Vs[4][64][64];      // [d][kv], 4-deep, xor-swizzled (32 KB)
    __shared__ u16 Ps[4][2][16][64];   // per-wave, per-set P (16 KB)
    // total LDS = 81920 B -> 2 blocks/CU exactly (grid 512 = 2/CU)

    u16 (*PsH)[64] = Ps[wid][0];
    u16 (*PsA)[64] = Ps[wid][1];

    const int rr8 = lane >> 3;
    const int cc8 = ((lane & 7) ^ rr8) * 8;  // s(row)=row&7
    const int swp = l15 & 7;                 // Ps chunk swizzle key

    // ones column for MFMA row-sum (bf16 1.0 = 0x3F80)
    short8 ones8;
#pragma unroll
    for (int i = 0; i < 8; ++i) ones8[i] = (short)0x3F80;

    // Q fragments for both q-sets (B-operand layout: lane n=l15 q-row, k=lq*8+j)
    short8 qfh[2], qfa[2];
#pragma unroll
    for (int ks = 0; ks < 2; ++ks) {
        qfh[ks] = *(const short8*)&Qb[(size_t)(qwh + l15) * HD + ks * 32 + lq * 8];
        qfa[ks] = *(const short8*)&Qb[(size_t)(qwa + l15) * HD + ks * 32 + lq * 8];
    }

    float4v Oh[4] = {}, Oa[4] = {};
    float4v lsh = {}, lsa = {};

    const int ntiles = qh + 1;               // 17..32
    // prologue: stage tiles 0 and 1; wait tile 0 landed (tile 1 in flight)
    ATTN_STAGE(0, 0)
    if (ntiles > 1) {
        ATTN_STAGE(1, 1)
        asm volatile("s_waitcnt vmcnt(4)" ::: "memory");
    } else {
        asm volatile("s_waitcnt vmcnt(0)" ::: "memory");
    }
    __builtin_amdgcn_s_barrier();

    for (int t = 0; t < ntiles; ++t) {
        const int slot = t & 3;
        if (t + 2 < ntiles) ATTN_STAGE((t + 2) & 3, t + 2)
        const u16 (*KsS)[64] = Ks[slot];
        const u16 (*VsS)[64] = Vs[slot];
        short8 kf[4][2];
#pragma unroll
        for (int nt = 0; nt < 4; ++nt) {
            int r_ = nt * 16 + l15;
            int sw = r_ & 7;
            kf[nt][0] = *(const short8*)&KsS[r_][(lq ^ sw) * 8];
            kf[nt][1] = *(const short8*)&KsS[r_][((lq + 4) ^ sw) * 8];
        }
        short8 vf[2][4];
#pragma unroll
        for (int kk = 0; kk < 2; ++kk)
#pragma unroll
            for (int nd = 0; nd < 4; ++nd) {
                int d = nd * 16 + l15;
                vf[kk][nd] = *(const short8*)&VsS[d][((kk * 4 + lq) ^ (d & 7)) * 8];
            }
        ATTN_QKSM(kf, t, qfh, PsH, qwh)
        if (t <= qa) ATTN_QKSM(kf, t, qfa, PsA, qwa)
        asm volatile("s_waitcnt lgkmcnt(0)" ::: "memory");
        ATTN_PV(PsH, vf, Oh, lsh)
        if (t <= qa) ATTN_PV(PsA, vf, Oa, lsa)
        // counted-vmcnt barrier: tile t+1's loads (oldest 4) drained, tile
        // t+2's 4 stay in flight across the barrier (T4 — never vmcnt(0)).
        if (t + 2 < ntiles) {
            asm volatile("s_waitcnt vmcnt(4) lgkmcnt(0)" ::: "memory");
        } else {
            asm volatile("s_waitcnt vmcnt(0) lgkmcnt(0)" ::: "memory");
        }
        __builtin_amdgcn_s_barrier();
    }

    ATTN_EPI(Oh, lsh, q0h)
    ATTN_EPI(Oa, lsa, q0a)
}

// ---------------------------------------------------------------------------
extern "C" void kernel_launch(void* const* d_in, const int* in_sizes, int n_in,
                              void* d_out, int out_size, void* d_ws, size_t ws_size,
                              hipStream_t stream) {
    const float* x  = (const float*)d_in[0];
    const float* wq = (const float*)d_in[1];
    const float* wk = (const float*)d_in[2];
    const float* wv = (const float*)d_in[3];
    const float* wo = (const float*)d_in[4];
    float* out = (float*)d_out;

    u16* ws  = (u16*)d_ws;
    u16* xb  = ws;                             // 4M : x bf16
    u16* Wt  = xb  + (size_t)4 * 1024 * 1024;  // 4M : 4 transposed weights
    u16* Qb  = Wt  + (size_t)4 * 1024 * 1024;  // 4M : Q [B,H,S,D] (pre-scaled)
    u16* Kb  = Qb  + (size_t)4 * 1024 * 1024;  // 4M : K [B,H,S,D]
    u16* Vtb = Kb  + (size_t)4 * 1024 * 1024;  // 4M : V^T [B,H,D,S]
    u16* ctx = Vtb + (size_t)4 * 1024 * 1024;  // 4M : ctx [B,S,E]

    prep_kernel<<<dim3(16, 16, 8), dim3(256), 0, stream>>>(x, wq, wk, wv, wo, xb, Wt);
    gemm_proj_kernel<<<dim3(8, 32, 3), dim3(256), 0, stream>>>(xb, Wt, Qb, Kb, Vtb);
    attn_kernel<<<dim3(32, 16), dim3(256), 0, stream>>>(Qb, Kb, Vtb, ctx);
    gemm_out_kernel<<<dim3(16, 32), dim3(256), 0, stream>>>(ctx, Wt + (size_t)3 * 1024 * 1024, out);
}

// Round 12
// 172.974 us; speedup vs baseline: 1.0169x; 1.0169x over previous
//
#include <hip/hip_runtime.h>
#include <hip/hip_bf16.h>

#define S_LEN 2048
#define EMB   1024
#define NH    16
#define HD    64
#define BATCH 2
#define MROWS (BATCH * S_LEN)   // 4096

typedef __attribute__((ext_vector_type(8))) short short8;   // 8 bf16 = 4 VGPR
typedef __attribute__((ext_vector_type(4))) float float4v;  // 4 fp32

#define MFMA16(a, b, c) __builtin_amdgcn_mfma_f32_16x16x32_bf16((a), (b), (c), 0, 0, 0)

typedef unsigned short u16;
typedef unsigned int   u32;

__device__ __forceinline__ u16 f2bf(float f) {
    union { float f; u32 u; } v; v.f = f;
    u32 u = v.u;
    return (u16)((u + 0x7fffu + ((u >> 16) & 1u)) >> 16);  // RNE
}

// packed fp32x2 -> bf16x2 (HW RNE on gfx950; fallback manual)
#if __has_builtin(__builtin_amdgcn_cvt_pk_bf16_f32)
typedef __attribute__((ext_vector_type(2))) __bf16 bfx2;
__device__ __forceinline__ u32 pkbf(float a, float b) {
    union { bfx2 v; u32 u; } c;
    c.v = __builtin_amdgcn_cvt_pk_bf16_f32(a, b);
    return c.u;
}
#else
__device__ __forceinline__ u32 pkbf(float a, float b) {
    return (u32)f2bf(a) | ((u32)f2bf(b) << 16);
}
#endif

#if __has_builtin(__builtin_amdgcn_exp2f)
#define EXP2(x) __builtin_amdgcn_exp2f(x)
#else
#define EXP2(x) exp2f(x)
#endif

// async 16B global->LDS (lds dest = wave-uniform base + lane*16)
typedef __attribute__((address_space(3))) unsigned char lds_u8;
typedef __attribute__((address_space(1))) const unsigned char glb_u8;
__device__ __forceinline__ void async_copy16(const void* g, void* l) {
    __builtin_amdgcn_global_load_lds((glb_u8*)g, (lds_u8*)l, 16, 0, 0);
}

// ---------------------------------------------------------------------------
// K0: fused prologue (R9-verified). z=0..3: convert+transpose weight z on
// 64x64 tiles — float4 (16 B/lane) reads, LDS [64][65] staging, uint2
// (4 bf16, 8 B/lane) packed stores via cvt_pk. Wq pre-scaled by 0.125*log2e.
// z=4..7: x -> bf16, 16 floats per thread.
// Coverage: 4 z x 256 blk x 256 thr x 16 = 4,194,304 floats = |x|.
// ---------------------------------------------------------------------------
__global__ __launch_bounds__(256) void prep_kernel(
    const float* __restrict__ x,
    const float* __restrict__ W0, const float* __restrict__ W1,
    const float* __restrict__ W2, const float* __restrict__ W3,
    u16* __restrict__ xb, u16* __restrict__ Wt) {
    const int z = blockIdx.z;
    const int tid = threadIdx.x;
    if (z >= 4) {
        int i = ((((z - 4) * 256) + blockIdx.y * 16 + blockIdx.x) * 256 + tid) * 16;
#pragma unroll
        for (int k = 0; k < 4; ++k) {
            float4 f = *(const float4*)(x + i + k * 4);
            uint2 o; o.x = pkbf(f.x, f.y); o.y = pkbf(f.z, f.w);
            *(uint2*)(xb + i + k * 4) = o;
        }
        return;
    }
    const float* W = (z == 0) ? W0 : (z == 1) ? W1 : (z == 2) ? W2 : W3;
    u16* dst = Wt + (size_t)z * EMB * EMB;
    const float sc = (z == 0) ? 0.18033688011112042f : 1.0f;
    __shared__ float tile[64][65];
    const int c0 = blockIdx.x * 64, r0 = blockIdx.y * 64;
    const int rv = tid & 15, rw = tid >> 4;
#pragma unroll
    for (int k = 0; k < 4; ++k) {
        int row = rw + 16 * k;
        float4 f = *(const float4*)&W[(size_t)(r0 + row) * EMB + c0 + rv * 4];
        tile[row][rv * 4 + 0] = f.x;
        tile[row][rv * 4 + 1] = f.y;
        tile[row][rv * 4 + 2] = f.z;
        tile[row][rv * 4 + 3] = f.w;
    }
    __syncthreads();
    const int rq = tid & 15, cw = tid >> 4;
#pragma unroll
    for (int k = 0; k < 4; ++k) {
        int cr = cw + 16 * k;
        float t0 = tile[rq * 4 + 0][cr] * sc;
        float t1 = tile[rq * 4 + 1][cr] * sc;
        float t2 = tile[rq * 4 + 2][cr] * sc;
        float t3 = tile[rq * 4 + 3][cr] * sc;
        uint2 o; o.x = pkbf(t0, t1); o.y = pkbf(t2, t3);
        *(uint2*)&dst[(size_t)(c0 + cr) * EMB + r0 + rq * 4] = o;
    }
}

// ---------------------------------------------------------------------------
// GEMM core (128x128): R1-measured version, reverted after R11's rolled-loop
// counted-vmcnt regression (+4us: runtime slot indexing broke compile-time
// addressing; 80cy MFMA/step can't absorb the overhead). BK=32, depth-1 LDS
// double-buffer, xor swizzle, prefetch before MFMAs, compile-time slots.
// ---------------------------------------------------------------------------
#define GEMM_STEP(B, KN)                                                                       \
    {                                                                                           \
        short8 a[4], b[4];                                                                      \
        _Pragma("unroll")                                                                       \
        for (int i = 0; i < 4; ++i) a[i] = *(const short8*)&As[B][wm * 64 + i * 16 + l15][ca];  \
        _Pragma("unroll")                                                                       \
        for (int j = 0; j < 4; ++j) b[j] = *(const short8*)&Bs[B][wn * 64 + j * 16 + l15][ca];  \
        if ((KN) < EMB) {                                                                       \
            for (int wl = wid; wl < 8; wl += 4) {                                               \
                async_copy16(&Ag[(size_t)(m0 + wl * 16 + rr) * EMB + (KN) + cc], &As[B ^ 1][wl * 16][0]); \
                async_copy16(&Bg[(size_t)(n0 + wl * 16 + rr) * EMB + (KN) + cc], &Bs[B ^ 1][wl * 16][0]); \
            }                                                                                   \
        }                                                                                       \
        _Pragma("unroll")                                                                       \
        for (int i = 0; i < 4; ++i)                                                             \
            _Pragma("unroll")                                                                   \
            for (int j = 0; j < 4; ++j)                                                         \
                acc[i][j] = MFMA16(a[i], b[j], acc[i][j]);                                      \
        __syncthreads();                                                                        \
    }

#define GEMM_CORE(A_, B_)                                                                      \
    const int tid = threadIdx.x;                                                                \
    const int lane = tid & 63, wid = tid >> 6;                                                  \
    const int wm = wid >> 1, wn = wid & 1;                                                      \
    const int l15 = lane & 15, lq = lane >> 4;                                                  \
    const int m0 = blockIdx.y * 128, n0 = blockIdx.x * 128;                                     \
    const u16* Ag = (A_);                                                                       \
    const u16* Bg = (B_);                                                                       \
    __shared__ u16 As[2][128][32];                                                              \
    __shared__ u16 Bs[2][128][32];                                                              \
    float4v acc[4][4] = {};                                                                     \
    const int rr = lane >> 2;                                                                   \
    const int cc = ((lane & 3) ^ ((rr >> 1) & 3)) * 8;                                          \
    const int ca = (lq ^ ((l15 >> 1) & 3)) * 8;                                                 \
    for (int wl = wid; wl < 8; wl += 4) {                                                       \
        async_copy16(&Ag[(size_t)(m0 + wl * 16 + rr) * EMB + cc], &As[0][wl * 16][0]);          \
        async_copy16(&Bg[(size_t)(n0 + wl * 16 + rr) * EMB + cc], &Bs[0][wl * 16][0]);          \
    }                                                                                           \
    __syncthreads();                                                                            \
    for (int k0 = 0; k0 < EMB; k0 += 64) {                                                      \
        GEMM_STEP(0, k0 + 32)                                                                   \
        GEMM_STEP(1, k0 + 64)                                                                   \
    }

// K2: fused 3-projection GEMM: z=0 Q[B,H,S,D], z=1 K[B,H,S,D], z=2 V^T[B,H,D,S]
__global__ __launch_bounds__(256) void gemm_proj_kernel(
    const u16* __restrict__ A, const u16* __restrict__ WtAll,
    u16* __restrict__ Qb, u16* __restrict__ Kb, u16* __restrict__ Vtb) {
    const int z = blockIdx.z;
    const u16* Wt = WtAll + (size_t)z * EMB * EMB;
    GEMM_CORE(A, Wt)
#pragma unroll
    for (int i = 0; i < 4; ++i)
#pragma unroll
        for (int j = 0; j < 4; ++j) {
            int mb = m0 + wm * 64 + i * 16 + lq * 4;      // 4 consecutive m
            int n  = n0 + wn * 64 + j * 16 + l15;
            int b_ = mb >> 11, s = mb & 2047;
            int h = n >> 6, d = n & 63;
            if (z == 2) {
                uint2 pv;
                pv.x = pkbf(acc[i][j][0], acc[i][j][1]);
                pv.y = pkbf(acc[i][j][2], acc[i][j][3]);
                *(uint2*)&Vtb[(((size_t)(b_ * NH + h) * HD + d) * S_LEN) + s] = pv;
            } else {
                u16* dst = (z == 1) ? Kb : Qb;
#pragma unroll
                for (int r = 0; r < 4; ++r)
                    dst[(((size_t)(b_ * NH + h) * S_LEN + s + r) * HD) + d] = f2bf(acc[i][j][r]);
            }
        }
}

// ---------------------------------------------------------------------------
// K4: output GEMM -> fp32 (R1-measured version). 128m x 64n tiles: grid
// (16,32) = 512 blocks.
// ---------------------------------------------------------------------------
__global__ __launch_bounds__(256) void gemm_out_kernel(
    const u16* __restrict__ A, const u16* __restrict__ Wt, float* __restrict__ out) {
    const int tid = threadIdx.x;
    const int lane = tid & 63, wid = tid >> 6;
    const int wm = wid >> 1, wn = wid & 1;
    const int l15 = lane & 15, lq = lane >> 4;
    const int m0 = blockIdx.y * 128, n0 = blockIdx.x * 64;
    __shared__ u16 As[2][128][32];
    __shared__ u16 Bs[2][64][32];
    float4v acc[4][2] = {};
    const int rr = lane >> 2;
    const int cc = ((lane & 3) ^ ((rr >> 1) & 3)) * 8;
    const int ca = (lq ^ ((l15 >> 1) & 3)) * 8;

#define GO_STAGE(B, KN)                                                                        \
    {                                                                                           \
        for (int wl = wid; wl < 8; wl += 4)                                                     \
            async_copy16(&A[(size_t)(m0 + wl * 16 + rr) * EMB + (KN) + cc], &As[B][wl * 16][0]);\
        async_copy16(&Wt[(size_t)(n0 + wid * 16 + rr) * EMB + (KN) + cc], &Bs[B][wid * 16][0]); \
    }
#define GO_STEP(B, KN)                                                                         \
    {                                                                                           \
        short8 a[4], b[2];                                                                      \
        _Pragma("unroll")                                                                       \
        for (int i = 0; i < 4; ++i) a[i] = *(const short8*)&As[B][wm * 64 + i * 16 + l15][ca];  \
        _Pragma("unroll")                                                                       \
        for (int j = 0; j < 2; ++j) b[j] = *(const short8*)&Bs[B][wn * 32 + j * 16 + l15][ca];  \
        if ((KN) < EMB) GO_STAGE(B ^ 1, KN)                                                     \
        _Pragma("unroll")                                                                       \
        for (int i = 0; i < 4; ++i)                                                             \
            _Pragma("unroll")                                                                   \
            for (int j = 0; j < 2; ++j)                                                         \
                acc[i][j] = MFMA16(a[i], b[j], acc[i][j]);                                      \
        __syncthreads();                                                                        \
    }

    GO_STAGE(0, 0)
    __syncthreads();
    for (int k0 = 0; k0 < EMB; k0 += 64) {
        GO_STEP(0, k0 + 32)
        GO_STEP(1, k0 + 64)
    }
#pragma unroll
    for (int i = 0; i < 4; ++i)
#pragma unroll
        for (int j = 0; j < 2; ++j)
#pragma unroll
            for (int r = 0; r < 4; ++r) {
                int m = m0 + wm * 64 + i * 16 + lq * 4 + r;
                int n = n0 + wn * 32 + j * 16 + l15;
                out[(size_t)m * EMB + n] = acc[i][j][r];
            }
}

// ---------------------------------------------------------------------------
// K3: flash attention (causal), S^T = K*Q^T, fixed-shift softmax (m=0).
// R12 = R10 (verified −3us) with DEPTH-3 prefetch: stage tile t+3 during
// tile t; barrier = s_waitcnt vmcnt(8) lgkmcnt(0) + s_barrier — tile t+1's
// loads drained, tiles t+2 AND t+3 (8 loads) stay in flight across the
// barrier, covering ~2x the L2 latency per drain vs R10's depth-2.
// Slot safety (4-ring): read t, landing t+1/t+2, issuing t+3 == t-1 mod 4;
// t-1's ds_reads completed before iteration t-1's barrier (lgkmcnt(0)),
// which all waves crossed before any wave issues stage(t+3). ntiles >= 17
// so prologue stages 0,1,2 unconditionally.
// LDS = Ks[4]+Vs[4]+Ps = 80 KiB -> 2 blocks/CU exactly (grid 512 = 2/CU).
// ---------------------------------------------------------------------------
#define ATTN_STAGE(SLOT, T)                                                                    \
    {                                                                                           \
        int kv0s = (T) * 64;                                                                    \
        u16 (*KsD)[64] = Ks[SLOT];                                                              \
        u16 (*VsD)[64] = Vs[SLOT];                                                              \
        for (int wl = wid; wl < 8; wl += 4) {                                                   \
            async_copy16(&Kb[(size_t)(kv0s + wl * 8 + rr8) * HD + cc8], &KsD[wl * 8][0]);       \
            async_copy16(&Vb[(size_t)(wl * 8 + rr8) * S_LEN + kv0s + cc8], &VsD[wl * 8][0]);    \
        }                                                                                       \
    }

// QK + mask + exp2 + pack + swizzled Ps write (no drain, no PV)
#define ATTN_QKSM(KF, T, QF, PS, QW)                                                           \
    {                                                                                           \
        const int kv0 = (T) * 64;                                                               \
        float4v sc[4];                                                                          \
        _Pragma("unroll")                                                                       \
        for (int nt = 0; nt < 4; ++nt) {                                                        \
            float4v c4 = {};                                                                    \
            c4 = MFMA16(KF[nt][0], QF[0], c4);                                                  \
            c4 = MFMA16(KF[nt][1], QF[1], c4);                                                  \
            sc[nt] = c4;                                                                        \
        }                                                                                       \
        if (kv0 + 63 > (QW)) {                                                                  \
            const int qi = (QW) + l15;                                                          \
            _Pragma("unroll")                                                                   \
            for (int nt = 0; nt < 4; ++nt)                                                      \
                _Pragma("unroll")                                                               \
                for (int r = 0; r < 4; ++r)                                                     \
                    if (kv0 + nt * 16 + lq * 4 + r > qi) sc[nt][r] = -__builtin_inff();         \
        }                                                                                       \
        _Pragma("unroll")                                                                       \
        for (int nt = 0; nt < 4; ++nt) {                                                        \
            float p0 = EXP2(sc[nt][0]);                                                         \
            float p1 = EXP2(sc[nt][1]);                                                         \
            float p2 = EXP2(sc[nt][2]);                                                         \
            float p3 = EXP2(sc[nt][3]);                                                         \
            uint2 pk;                                                                           \
            pk.x = pkbf(p0, p1);                                                                \
            pk.y = pkbf(p2, p3);                                                                \
            *(uint2*)((char*)&PS[l15][0] +                                                      \
                      (((nt * 2 + (lq >> 1)) ^ swp) * 16 + (lq & 1) * 8)) = pk;                 \
        }                                                                                       \
    }

#define ATTN_PV(PS, VF, OO, LS)                                                                \
    {                                                                                           \
        _Pragma("unroll")                                                                       \
        for (int kk = 0; kk < 2; ++kk) {                                                        \
            short8 pf = *(const short8*)((const char*)&PS[l15][0] +                             \
                                         (((kk * 4 + lq) ^ swp) * 16));                         \
            _Pragma("unroll")                                                                   \
            for (int nd = 0; nd < 4; ++nd)                                                      \
                OO[nd] = MFMA16(pf, VF[kk][nd], OO[nd]);                                        \
            LS = MFMA16(pf, ones8, LS);                                                         \
        }                                                                                       \
    }

#define ATTN_EPI(OO, LS, Q0)                                                                   \
    {                                                                                           \
        _Pragma("unroll")                                                                       \
        for (int r = 0; r < 4; ++r) {                                                           \
            float lr = 1.f / LS[r];                                                             \
            int s = (Q0) + wid * 16 + lq * 4 + r;                                               \
            size_t base = ((size_t)b * S_LEN + s) * EMB + h * HD;                               \
            _Pragma("unroll")                                                                   \
            for (int nd = 0; nd < 4; ++nd)                                                      \
                ctx[base + nd * 16 + l15] = f2bf(OO[nd][r] * lr);                               \
        }                                                                                       \
    }

__global__ __launch_bounds__(256, 2) void attn_kernel(
    const u16* __restrict__ Q, const u16* __restrict__ K,
    const u16* __restrict__ Vt, u16* __restrict__ ctx) {
    const int tid = threadIdx.x;
    const int lane = tid & 63, wid = tid >> 6;
    const int l15 = lane & 15, lq = lane >> 4;
    const int bh = blockIdx.x;               // x fastest: same-bh blocks same XCD
    const int b = bh >> 4, h = bh & 15;
    const int y = blockIdx.y;                // 0..15
    const int qa = y, qh = 31 - y;           // paired q-tiles: 33 units/block
    const int q0h = qh * 64, q0a = qa * 64;
    const int qwh = q0h + wid * 16, qwa = q0a + wid * 16;

    const u16* Qb = Q + (size_t)bh * S_LEN * HD;
    const u16* Kb = K + (size_t)bh * S_LEN * HD;
    const u16* Vb = Vt + (size_t)bh * HD * S_LEN;

    __shared__ u16 Ks[4][64][64];      // [kv][d], 4-deep, xor-swizzled (32 KB)
    __shared__ u16 Vs[4][64][64];      // [d][kv], 4-deep, xor-swizzled (32 KB)
    __shared__ u16 Ps[4][2][16][64];   // per-wave, per-set P (16 KB)
    // total LDS = 81920 B -> 2 blocks/CU exactly (grid 512 = 2/CU)

    u16 (*PsH)[64] = Ps[wid][0];
    u16 (*PsA)[64] = Ps[wid][1];

    const int rr8 = lane >> 3;
    const int cc8 = ((lane & 7) ^ rr8) * 8;  // s(row)=row&7
    const int swp = l15 & 7;                 // Ps chunk swizzle key

    // ones column for MFMA row-sum (bf16 1.0 = 0x3F80)
    short8 ones8;
#pragma unroll
    for (int i = 0; i < 8; ++i) ones8[i] = (short)0x3F80;

    // Q fragments for both q-sets (B-operand layout: lane n=l15 q-row, k=lq*8+j)
    short8 qfh[2], qfa[2];
#pragma unroll
    for (int ks = 0; ks < 2; ++ks) {
        qfh[ks] = *(const short8*)&Qb[(size_t)(qwh + l15) * HD + ks * 32 + lq * 8];
        qfa[ks] = *(const short8*)&Qb[(size_t)(qwa + l15) * HD + ks * 32 + lq * 8];
    }

    float4v Oh[4] = {}, Oa[4] = {};
    float4v lsh = {}, lsa = {};

    const int ntiles = qh + 1;               // 17..32 (always >= 17)
    // prologue: stage tiles 0,1,2; wait tile 0 landed (1 and 2 in flight)
    ATTN_STAGE(0, 0)
    ATTN_STAGE(1, 1)
    ATTN_STAGE(2, 2)
    asm volatile("s_waitcnt vmcnt(8)" ::: "memory");
    __builtin_amdgcn_s_barrier();

    for (int t = 0; t < ntiles; ++t) {
        const int slot = t & 3;
        if (t + 3 < ntiles) ATTN_STAGE((t + 3) & 3, t + 3)
        const u16 (*KsS)[64] = Ks[slot];
        const u16 (*VsS)[64] = Vs[slot];
        short8 kf[4][2];
#pragma unroll
        for (int nt = 0; nt < 4; ++nt) {
            int r_ = nt * 16 + l15;
            int sw = r_ & 7;
            kf[nt][0] = *(const short8*)&KsS[r_][(lq ^ sw) * 8];
            kf[nt][1] = *(const short8*)&KsS[r_][((lq + 4) ^ sw) * 8];
        }
        short8 vf[2][4];
#pragma unroll
        for (int kk = 0; kk < 2; ++kk)
#pragma unroll
            for (int nd = 0; nd < 4; ++nd) {
                int d = nd * 16 + l15;
                vf[kk][nd] = *(const short8*)&VsS[d][((kk * 4 + lq) ^ (d & 7)) * 8];
            }
        ATTN_QKSM(kf, t, qfh, PsH, qwh)
        if (t <= qa) ATTN_QKSM(kf, t, qfa, PsA, qwa)
        asm volatile("s_waitcnt lgkmcnt(0)" ::: "memory");
        ATTN_PV(PsH, vf, Oh, lsh)
        if (t <= qa) ATTN_PV(PsA, vf, Oa, lsa)
        // counted-vmcnt barrier: tile t+1 drained; t+2 and t+3 (8 loads)
        // stay in flight across the barrier (T4 — never vmcnt(0) mid-loop).
        if (t + 3 < ntiles) {
            asm volatile("s_waitcnt vmcnt(8) lgkmcnt(0)" ::: "memory");
        } else if (t + 2 < ntiles) {
            asm volatile("s_waitcnt vmcnt(4) lgkmcnt(0)" ::: "memory");
        } else {
            asm volatile("s_waitcnt vmcnt(0) lgkmcnt(0)" ::: "memory");
        }
        __builtin_amdgcn_s_barrier();
    }

    ATTN_EPI(Oh, lsh, q0h)
    ATTN_EPI(Oa, lsa, q0a)
}

// ---------------------------------------------------------------------------
extern "C" void kernel_launch(void* const* d_in, const int* in_sizes, int n_in,
                              void* d_out, int out_size, void* d_ws, size_t ws_size,
                              hipStream_t stream) {
    const float* x  = (const float*)d_in[0];
    const float* wq = (const float*)d_in[1];
    const float* wk = (const float*)d_in[2];
    const float* wv = (const float*)d_in[3];
    const float* wo = (const float*)d_in[4];
    float* out = (float*)d_out;

    u16* ws  = (u16*)d_ws;
    u16* xb  = ws;                             // 4M : x bf16
    u16* Wt  = xb  + (size_t)4 * 1024 * 1024;  // 4M : 4 transposed weights
    u16* Qb  = Wt  + (size_t)4 * 1024 * 1024;  // 4M : Q [B,H,S,D] (pre-scaled)
    u16* Kb  = Qb  + (size_t)4 * 1024 * 1024;  // 4M : K [B,H,S,D]
    u16* Vtb = Kb  + (size_t)4 * 1024 * 1024;  // 4M : V^T [B,H,D,S]
    u16* ctx = Vtb + (size_t)4 * 1024 * 1024;  // 4M : ctx [B,S,E]

    prep_kernel<<<dim3(16, 16, 8), dim3(256), 0, stream>>>(x, wq, wk, wv, wo, xb, Wt);
    gemm_proj_kernel<<<dim3(8, 32, 3), dim3(256), 0, stream>>>(xb, Wt, Qb, Kb, Vtb);
    attn_kernel<<<dim3(32, 16), dim3(256), 0, stream>>>(Qb, Kb, Vtb, ctx);
    gemm_out_kernel<<<dim3(16, 32), dim3(256), 0, stream>>>(ctx, Wt + (size_t)3 * 1024 * 1024, out);
}